// Round 3
// baseline (194.526 us; speedup 1.0000x reference)
//
#include <hip/hip_runtime.h>

#define NN 50000
#define NE 800000
#define EP (NE + NN)      // edges + self loops = 850000
#define NG 128
#define F 128
#define NBE 208           // edge-pass blocks
#define EPB 4096          // edges per block (208*4096 >= EP)
#define NBUCK 196         // dst buckets of 256 nodes
#define BCAP 6144         // per-bucket edge cap (mean 4352, max ~4650)
#define GB1 782           // gemm1 blocks: (NN+63)/64

typedef __attribute__((ext_vector_type(8))) short short8;
typedef __attribute__((ext_vector_type(4))) float float4v;
typedef __attribute__((ext_vector_type(2))) float float2v;
union U8 { uint4 u; short8 s; };

__device__ inline unsigned int bf16rn(float x) {   // RNE round to bf16 (low 16 bits)
    unsigned int u = __float_as_uint(x);
    u += 0x7fffu + ((u >> 16) & 1u);
    return u >> 16;
}
__device__ inline unsigned int pack2(float a, float b) {
    return bf16rn(a) | (bf16rn(b) << 16);
}
// 8 bf16 (uint4) -> 4 packed-f32 fma's into acc[0..3] (v_pk_fma_f32 path)
__device__ inline void bf8_fma2(float2v* acc, float w, uint4 hv) {
    const float2v wv = {w, w};
    float2v p0, p1, p2, p3;
    p0.x = __uint_as_float(hv.x << 16); p0.y = __uint_as_float(hv.x & 0xffff0000u);
    p1.x = __uint_as_float(hv.y << 16); p1.y = __uint_as_float(hv.y & 0xffff0000u);
    p2.x = __uint_as_float(hv.z << 16); p2.y = __uint_as_float(hv.z & 0xffff0000u);
    p3.x = __uint_as_float(hv.w << 16); p3.y = __uint_as_float(hv.w & 0xffff0000u);
    acc[0] += wv * p0;
    acc[1] += wv * p1;
    acc[2] += wv * p2;
    acc[3] += wv * p3;
}

// One-shot: pack W1 and W2 fp32 [128][128] into MFMA B-fragments (bf16).
// Also zeroes gscr (block 16) and cnt (block 16) — both written later.
__global__ void pack_wfrag2(const float* __restrict__ W1, const float* __restrict__ W2,
                            uint4* __restrict__ wf, float* __restrict__ gscr,
                            int* __restrict__ cnt) {
    const int p = blockIdx.x * blockDim.x + threadIdx.x;   // 0..4351
    if (p >= 4096) {                    // block 16: zero gscr + cnt
        const int t = threadIdx.x;
        for (int i = t; i < NG * 32; i += 256) gscr[i] = 0.f;
        for (int i = t; i < NBUCK; i += 256) cnt[i] = 0;
        return;
    }
    const float* W = (p < 2048) ? W1 : W2;
    const int q = p & 2047;
    const int f = q >> 6, l = q & 63;
    const int kt = f >> 3, nt = f & 7;
    const int rb = kt * 32 + ((l >> 4) << 3);
    const int col = nt * 16 + (l & 15);
    const float* wp = W + (size_t)rb * F + col;
    uint4 pk;
    pk.x = pack2(wp[0],     wp[F]);
    pk.y = pack2(wp[2 * F], wp[3 * F]);
    pk.z = pack2(wp[4 * F], wp[5 * F]);
    pk.w = pack2(wp[6 * F], wp[7 * F]);
    wf[p] = pk;
}

// gemm1 body: C[N,128] = x[N,128] @ W1 (fp32 A converted in-register) via
// v_mfma_f32_16x16x32_bf16, plus fused att_src/att_dst row projections.
__device__ __forceinline__ void gemm1_body(
        const float* __restrict__ Af, const uint4* __restrict__ wf,
        unsigned short* __restrict__ Cb,
        const float* __restrict__ att_src, const float* __restrict__ att_dst,
        float* __restrict__ asrc, float* __restrict__ adst, int bid) {
    const int t = threadIdx.x;
    const int wave = t >> 6, lane = t & 63;
    const int m0 = bid * 64 + wave * 16;
    const int arow = m0 + (lane & 15);
    const int kq = (lane >> 4) << 3;
    U8 a[4];
#pragma unroll
    for (int kt = 0; kt < 4; ++kt) {
        if (arow < NN) {
            const float* ap = Af + (size_t)arow * F + kt * 32 + kq;
            const float4 f0 = *(const float4*)ap;
            const float4 f1 = *(const float4*)(ap + 4);
            a[kt].u = make_uint4(pack2(f0.x, f0.y), pack2(f0.z, f0.w),
                                 pack2(f1.x, f1.y), pack2(f1.z, f1.w));
        } else {
            a[kt].u = make_uint4(0, 0, 0, 0);
        }
    }
    const int ccol = lane & 15;
    const int crow0 = m0 + ((lane >> 4) << 2);
    float ps[4] = {}, pd[4] = {};
    for (int nt = 0; nt < 8; nt += 2) {
        float4v acc0 = {0.f, 0.f, 0.f, 0.f}, acc1 = {0.f, 0.f, 0.f, 0.f};
#pragma unroll
        for (int kt = 0; kt < 4; ++kt) {
            U8 b0, b1;
            b0.u = wf[(kt * 8 + nt) * 64 + lane];
            b1.u = wf[(kt * 8 + nt + 1) * 64 + lane];
            acc0 = __builtin_amdgcn_mfma_f32_16x16x32_bf16(a[kt].s, b0.s, acc0, 0, 0, 0);
            acc1 = __builtin_amdgcn_mfma_f32_16x16x32_bf16(a[kt].s, b1.s, acc1, 0, 0, 0);
        }
#pragma unroll
        for (int r = 0; r < 4; ++r) {
            const int row = crow0 + r;
            if (row < NN) {
                Cb[(size_t)row * F + nt * 16 + ccol]       = (unsigned short)bf16rn(acc0[r]);
                Cb[(size_t)row * F + (nt + 1) * 16 + ccol] = (unsigned short)bf16rn(acc1[r]);
            }
        }
        const float as0 = att_src[nt * 16 + ccol], as1 = att_src[(nt + 1) * 16 + ccol];
        const float ad0 = att_dst[nt * 16 + ccol], ad1 = att_dst[(nt + 1) * 16 + ccol];
#pragma unroll
        for (int r = 0; r < 4; ++r) {
            ps[r] += acc0[r] * as0 + acc1[r] * as1;
            pd[r] += acc0[r] * ad0 + acc1[r] * ad1;
        }
    }
#pragma unroll
    for (int r = 0; r < 4; ++r) {
        float s = ps[r], d = pd[r];
#pragma unroll
        for (int o = 8; o; o >>= 1) { s += __shfl_xor(s, o); d += __shfl_xor(d, o); }
        const int row = crow0 + r;
        if (ccol == 0 && row < NN) { asrc[row] = s; adst[row] = d; }
    }
}

// ---- Fused: gemm1 (blocks [0,GB1)) + CSR bucket scatter (blocks [GB1,GB1+NBE)).
__global__ __launch_bounds__(256) void gemm1_count_scatter(
        const float* __restrict__ x, const uint4* __restrict__ wf1,
        unsigned short* __restrict__ h1b,
        const float* __restrict__ att_src, const float* __restrict__ att_dst,
        float* __restrict__ asrc, float* __restrict__ adst,
        const int* __restrict__ ei, int* __restrict__ cur,
        unsigned int* __restrict__ ebuf) {
    if (blockIdx.x < GB1) {
        gemm1_body(x, wf1, h1b, att_src, att_dst, asrc, adst, blockIdx.x);
        return;
    }
    __shared__ int lcnt[NBUCK];
    __shared__ int lbase[NBUCK];
    const int t = threadIdx.x, b = blockIdx.x - GB1;
    for (int i = t; i < NBUCK; i += 256) lcnt[i] = 0;
    __syncthreads();
    const int e0 = b * EPB;
    int sarr[EPB / 256], darr[EPB / 256];
#pragma unroll
    for (int i = 0; i < EPB / 256; ++i) {
        const int e = e0 + i * 256 + t;
        int s = 0, d = -1;
        if (e < EP) {
            if (e < NE) { s = ei[e]; d = ei[NE + e]; } else { s = d = e - NE; }
            atomicAdd(&lcnt[d >> 8], 1);
        }
        sarr[i] = s; darr[i] = d;
    }
    __syncthreads();
    for (int i = t; i < NBUCK; i += 256) {
        lbase[i] = atomicAdd(&cur[i], lcnt[i]);   // reserve contiguous run
        lcnt[i] = 0;                              // reuse as local cursor
    }
    __syncthreads();
#pragma unroll
    for (int i = 0; i < EPB / 256; ++i) {
        const int d = darr[i];
        if (d >= 0) {
            const int bk = d >> 8;
            const int p = lbase[bk] + atomicAdd(&lcnt[bk], 1);
            ebuf[(size_t)bk * BCAP + p] = (unsigned int)sarr[i] | ((unsigned int)(d & 255) << 16);
        }
    }
}

// ---- bucket_sort + edge softmax: per-bucket LDS counting sort, then compute
// per-edge ev = exp(leaky(asrc[src]+adst[dst])) at the sorted position, sum
// den per dst node (thread t owns node g*256+t's run), and emit a
// PRE-NORMALIZED (src, alpha) uint2 stream. The GAT gather then needs no
// asrc gather / exp / den reduction — one memory stage instead of two.
// LDS: earr 24K + evarr 24K + out16 12K + ecnt/epre 2K + adst_s 1K = 63K
// (grid 196 < 256 CUs: one block per CU, so high LDS costs nothing).
__global__ __launch_bounds__(256) void bucket_sort(
        const unsigned int* __restrict__ ebuf, const int* __restrict__ cnt,
        const float* __restrict__ asrc, const float* __restrict__ adst,
        int* __restrict__ row_start, uint2* __restrict__ ca,
        int* __restrict__ deg, float* __restrict__ dinv) {
    __shared__ unsigned int earr[BCAP];
    __shared__ float evarr[BCAP];
    __shared__ unsigned short out16[BCAP];
    __shared__ int ecnt[256], epre[256];
    __shared__ float adst_s[256];
    const int t = threadIdx.x, g = blockIdx.x;
    const int m = cnt[g];
    const int n = g * 256 + t;
    adst_s[t] = (n < NN) ? adst[n] : 0.f;
    const unsigned int* src = ebuf + (size_t)g * BCAP;
    ecnt[t] = 0;
    __syncthreads();
    for (int i = t; i < m; i += 256) {
        const unsigned int v = src[i];
        earr[i] = v;
        atomicAdd(&ecnt[v >> 16], 1);
    }
    __syncthreads();
    const int v0 = ecnt[t];
    epre[t] = v0;
    __syncthreads();
    for (int o = 1; o < 256; o <<= 1) {
        const int u = (t >= o) ? epre[t - o] : 0;
        __syncthreads();
        epre[t] += u;
        __syncthreads();
    }
    const int my_excl = epre[t] - v0;
    if (n < NN) {
        row_start[n] = g * BCAP + my_excl;
        deg[n] = v0;                               // >= 1 (self loop)
        dinv[n] = rsqrtf((float)v0);
    }
    ecnt[t] = my_excl;
    __syncthreads();
#pragma unroll 4
    for (int i = t; i < m; i += 256) {             // sort scatter + edge score
        const unsigned int v = earr[i];
        const int s  = (int)(v & 0xffffu);
        const int dl = (int)(v >> 16);
        const int p  = atomicAdd(&ecnt[dl], 1);
        out16[p] = (unsigned short)s;
        float sc = asrc[s] + adst_s[dl];
        sc = sc > 0.f ? sc : 0.2f * sc;
        evarr[p] = __expf(sc);
    }
    __syncthreads();
    if (n < NN) {                                  // per-node normalize + emit
        uint2* cap = ca + (size_t)g * BCAP;
        float den = 0.f;
        for (int k = 0; k < v0; ++k) den += evarr[my_excl + k];
        const float inv = 1.f / den;               // den > 0 (self loop)
        for (int k = 0; k < v0; ++k) {
            uint2 w;
            w.x = (unsigned int)out16[my_excl + k];
            w.y = __float_as_uint(evarr[my_excl + k] * inv);
            cap[my_excl + k] = w;
        }
    }
}

// ---- GAT gather fused with gemm2: quarter-per-node gather (16 lanes/node,
// 16 nodes/block, grid exact NN/16). Weights are pre-normalized alphas from
// the ca stream — single sequential 8B load per edge, shfl broadcast, row
// load, FMA. Then the block's 16 rows form one MFMA 16x16 A-tile: stage
// post-ReLU bf16 rows in LDS (pad 17), barrier, each wave computes 2
// nt-columns of h2 = h_gat @ W2, scales by dinv[node], stores h2b.
__global__ __launch_bounds__(256) void gat_gemm2(
        const int* __restrict__ row_start, const int* __restrict__ deg,
        const uint2* __restrict__ ca,
        const unsigned short* __restrict__ hb, const float* __restrict__ bias,
        const uint4* __restrict__ wf2, const float* __restrict__ dinv,
        unsigned short* __restrict__ h2b) {
    __shared__ uint4 ldsA[16][17];                  // 16 nodes x 128 bf16, pad 17
    const int lane = threadIdx.x & 63;
    const int qid  = threadIdx.x >> 4;              // 0..15: node slot in block
    const int n    = blockIdx.x * 16 + qid;         // grid exact: 3125*16 = 50000
    const int lanesub = lane & 15;
    const int qb   = lane & 48;                     // quarter base lane
    const int qo   = lanesub << 3;                  // 8 channels per lane
    const int lo = row_start[n], hi = lo + deg[n];
    float2v acc[4];
#pragma unroll
    for (int i = 0; i < 4; ++i) acc[i] = (float2v){0.f, 0.f};
    for (int base = lo; base < hi; base += 16) {
        const int cnt = min(16, hi - base);
        int sv = 0; float ev = 0.f;
        if (lanesub < cnt) {
            const uint2 e = ca[base + lanesub];
            sv = (int)e.x; ev = __uint_as_float(e.y);
        }
        for (int j = 0; j < cnt; j += 8) {          // slots past cnt have ev=0
            int ss[8]; float ww[8]; uint4 hh[8];
#pragma unroll
            for (int k = 0; k < 8; ++k) {
                ss[k] = __shfl(sv, qb + j + k);
                ww[k] = __shfl(ev, qb + j + k);
            }
#pragma unroll
            for (int k = 0; k < 8; ++k)
                hh[k] = *(const uint4*)(hb + (size_t)ss[k] * F + qo);
#pragma unroll
            for (int k = 0; k < 8; ++k) bf8_fma2(acc, ww[k], hh[k]);
        }
    }
    const float4 b0 = *(const float4*)(bias + qo);
    const float4 b1 = *(const float4*)(bias + qo + 4);
    float v[8];
    v[0] = acc[0].x + b0.x; v[1] = acc[0].y + b0.y;
    v[2] = acc[1].x + b0.z; v[3] = acc[1].y + b0.w;
    v[4] = acc[2].x + b1.x; v[5] = acc[2].y + b1.y;
    v[6] = acc[3].x + b1.z; v[7] = acc[3].y + b1.w;
#pragma unroll
    for (int i = 0; i < 8; ++i) v[i] = v[i] > 0.f ? v[i] : 0.f;
    uint4 pk;
    pk.x = pack2(v[0], v[1]); pk.y = pack2(v[2], v[3]);
    pk.z = pack2(v[4], v[5]); pk.w = pack2(v[6], v[7]);
    ldsA[qid][lanesub] = pk;
    __syncthreads();
    // ---- gemm2 phase: wave w computes nt = 2w, 2w+1
    const int wave = threadIdx.x >> 6;
    U8 a[4];
#pragma unroll
    for (int kt = 0; kt < 4; ++kt)
        a[kt].u = ldsA[lane & 15][kt * 4 + (lane >> 4)];
    const int nt = wave * 2;
    float4v acc0 = {0.f, 0.f, 0.f, 0.f}, acc1 = {0.f, 0.f, 0.f, 0.f};
#pragma unroll
    for (int kt = 0; kt < 4; ++kt) {
        U8 b0f, b1f;
        b0f.u = wf2[(kt * 8 + nt) * 64 + lane];
        b1f.u = wf2[(kt * 8 + nt + 1) * 64 + lane];
        acc0 = __builtin_amdgcn_mfma_f32_16x16x32_bf16(a[kt].s, b0f.s, acc0, 0, 0, 0);
        acc1 = __builtin_amdgcn_mfma_f32_16x16x32_bf16(a[kt].s, b1f.s, acc1, 0, 0, 0);
    }
    const int ccol = lane & 15;
    const int crow0 = (lane >> 4) << 2;
#pragma unroll
    for (int r = 0; r < 4; ++r) {
        const int node = blockIdx.x * 16 + crow0 + r;
        const float rs = dinv[node];
        h2b[(size_t)node * F + nt * 16 + ccol]       = (unsigned short)bf16rn(acc0[r] * rs);
        h2b[(size_t)node * F + (nt + 1) * 16 + ccol] = (unsigned short)bf16rn(acc1[r] * rs);
    }
}

// ---- GCN gather + pool, quarter-per-node (pre-scaled h2 rows; tail slots
// predicated with w=0, a quarter-uniform test).
__global__ __launch_bounds__(256) void gcn_gather_pool(
        const int* __restrict__ row_start, const int* __restrict__ deg,
        const uint2* __restrict__ ca,
        const float* __restrict__ dinv, const unsigned short* __restrict__ hb,
        const float* __restrict__ bias, const int* __restrict__ batch,
        const float* __restrict__ Wf, float* __restrict__ gscr) {
    __shared__ int   sg[16];
    __shared__ float sp0[16], sp1[16];
    const int lane = threadIdx.x & 63;
    const int qid  = threadIdx.x >> 4;
    const int n    = blockIdx.x * 16 + qid;
    const int lanesub = lane & 15;
    const int qb   = lane & 48;
    const int qo   = lanesub << 3;
    const int lo = row_start[n], hi = lo + deg[n];
    const float dn = dinv[n];
    float2v acc[4];
#pragma unroll
    for (int i = 0; i < 4; ++i) acc[i] = (float2v){0.f, 0.f};
    for (int base = lo; base < hi; base += 16) {
        const int cnt = min(16, hi - base);
        int sv = 0;
        if (lanesub < cnt) sv = (int)ca[base + lanesub].x;
        for (int j = 0; j < cnt; j += 8) {
            int ss[8]; uint4 hh[8];
#pragma unroll
            for (int k = 0; k < 8; ++k) ss[k] = __shfl(sv, qb + j + k);
#pragma unroll
            for (int k = 0; k < 8; ++k)
                hh[k] = *(const uint4*)(hb + (size_t)ss[k] * F + qo);
#pragma unroll
            for (int k = 0; k < 8; ++k) {
                const float w = (j + k < cnt) ? 1.f : 0.f;   // quarter-uniform
                bf8_fma2(acc, w, hh[k]);
            }
        }
    }
    const float4 b0 = *(const float4*)(bias + qo);
    const float4 b1 = *(const float4*)(bias + qo + 4);
    float v[8];
    v[0] = fmaf(acc[0].x, dn, b0.x); v[1] = fmaf(acc[0].y, dn, b0.y);
    v[2] = fmaf(acc[1].x, dn, b0.z); v[3] = fmaf(acc[1].y, dn, b0.w);
    v[4] = fmaf(acc[2].x, dn, b1.x); v[5] = fmaf(acc[2].y, dn, b1.y);
    v[6] = fmaf(acc[3].x, dn, b1.z); v[7] = fmaf(acc[3].y, dn, b1.w);
#pragma unroll
    for (int i = 0; i < 8; ++i) v[i] = v[i] > 0.f ? v[i] : 0.f;
    const float4 w0 = *(const float4*)(Wf + qo * 2);
    const float4 w1 = *(const float4*)(Wf + qo * 2 + 4);
    const float4 w2 = *(const float4*)(Wf + qo * 2 + 8);
    const float4 w3 = *(const float4*)(Wf + qo * 2 + 12);
    float p0 = v[0]*w0.x + v[1]*w0.z + v[2]*w1.x + v[3]*w1.z +
               v[4]*w2.x + v[5]*w2.z + v[6]*w3.x + v[7]*w3.z;
    float p1 = v[0]*w0.y + v[1]*w0.w + v[2]*w1.y + v[3]*w1.w +
               v[4]*w2.y + v[5]*w2.w + v[6]*w3.y + v[7]*w3.w;
#pragma unroll
    for (int o = 8; o; o >>= 1) { p0 += __shfl_xor(p0, o); p1 += __shfl_xor(p1, o); }
    if (lanesub == 0) { sg[qid] = batch[n]; sp0[qid] = p0; sp1[qid] = p1; }
    __syncthreads();
    if (threadIdx.x == 0) {
#pragma unroll 1
        for (int w = 0; w < 16; ++w) {
            const int g = sg[w];
            if (g < 0) continue;
            float q0 = sp0[w], q1 = sp1[w];
            for (int u = w + 1; u < 16; ++u) {
                if (sg[u] == g) { q0 += sp0[u]; q1 += sp1[u]; sg[u] = -1; }
            }
            atomicAdd(gscr + g * 32,     q0);
            atomicAdd(gscr + g * 32 + 1, q1);
        }
    }
}

__global__ void finalize(const float* __restrict__ gscr, const int* __restrict__ batch,
                         const float* __restrict__ bf, float* __restrict__ out) {
    const int g = threadIdx.x;   // 128
    int lo = 0, hi = NN;
    while (lo < hi) { int m = (lo + hi) >> 1; if (batch[m] < g) lo = m + 1; else hi = m; }
    int lo2 = lo, hi2 = NN;
    while (lo2 < hi2) { int m = (lo2 + hi2) >> 1; if (batch[m] < g + 1) lo2 = m + 1; else hi2 = m; }
    const float inv = 1.f / fmaxf((float)(lo2 - lo), 1.f);
    out[g * 2]     = gscr[g * 32]     * inv + bf[0];
    out[g * 2 + 1] = gscr[g * 32 + 1] * inv + bf[1];
}

extern "C" void kernel_launch(void* const* d_in, const int* in_sizes, int n_in,
                              void* d_out, int out_size, void* d_ws, size_t ws_size,
                              hipStream_t stream) {
    const float* x       = (const float*)d_in[0];
    const float* W1      = (const float*)d_in[1];
    const float* att_src = (const float*)d_in[2];
    const float* att_dst = (const float*)d_in[3];
    const float* b1      = (const float*)d_in[4];
    const float* W2      = (const float*)d_in[5];
    const float* b2      = (const float*)d_in[6];
    const float* Wf      = (const float*)d_in[7];
    const float* bf      = (const float*)d_in[8];
    const int*   ei      = (const int*)d_in[9];
    const int*   batch   = (const int*)d_in[10];
    float* out = (float*)d_out;

    // layout: 16B-aligned first, then descending alignment
    uint4* wf1       = (uint4*)d_ws;                                // [2048] W1 frags (32 KB)
    uint4* wf2       = wf1 + 2048;                                  // [2048] W2 frags (32 KB)
    uint2* ca        = (uint2*)(wf2 + 2048);                        // [NBUCK*BCAP] (src, alpha)
    unsigned int* ebuf = (unsigned int*)(ca + (size_t)NBUCK * BCAP);// [NBUCK*BCAP]
    unsigned short* h1b = (unsigned short*)(ebuf + (size_t)NBUCK * BCAP); // [NN*F] bf16 (16B-aligned)
    unsigned short* h2b = h1b + (size_t)NN * F;                     // [NN*F] bf16 pre-scaled
    float* asrc      = (float*)(h2b + (size_t)NN * F);              // [NN]
    float* adst      = asrc + NN;                                   // [NN]
    float* dinv      = adst + NN;                                   // [NN]
    float* gscr      = dinv + NN;                                   // [NG*32]
    int*   row_start = (int*)(gscr + NG * 32);                      // [NN]
    int*   deg       = row_start + NN;                              // [NN]
    int*   cnt       = deg + NN;                                    // [NBUCK]

    // one-shot weight packing (+ gscr/cnt zeroing)
    pack_wfrag2<<<17, 256, 0, stream>>>(W1, W2, wf1, gscr, cnt);
    // gemm1 and CSR scatter are independent: one fused dispatch
    gemm1_count_scatter<<<GB1 + NBE, 256, 0, stream>>>(x, wf1, h1b, att_src, att_dst,
                                                       asrc, adst, ei, cnt, ebuf);
    bucket_sort<<<NBUCK, 256, 0, stream>>>(ebuf, cnt, asrc, adst,
                                           row_start, ca, deg, dinv);
    gat_gemm2<<<NN / 16, 256, 0, stream>>>(row_start, deg, ca, h1b, b1, wf2, dinv, h2b);
    gcn_gather_pool<<<NN / 16, 256, 0, stream>>>(row_start, deg, ca, dinv, h2b, b2,
                                                 batch, Wf, gscr);
    finalize<<<1, NG, 0, stream>>>(gscr, batch, bf, out);
}

// Round 4
// 190.493 us; speedup vs baseline: 1.0212x; 1.0212x over previous
//
#include <hip/hip_runtime.h>

#define NN 50000
#define NE 800000
#define EP (NE + NN)      // edges + self loops = 850000
#define NG 128
#define F 128
#define NBE 208           // edge-pass blocks
#define EPB 4096          // edges per block (208*4096 >= EP)
#define NBUCK 196         // dst buckets of 256 nodes
#define BCAP 6144         // per-bucket edge cap (mean 4352, max ~4650)
#define GB1 782           // gemm1 blocks: (NN+63)/64

typedef __attribute__((ext_vector_type(8))) short short8;
typedef __attribute__((ext_vector_type(4))) float float4v;
typedef __attribute__((ext_vector_type(2))) float float2v;
union U8 { uint4 u; short8 s; };

__device__ inline unsigned int bf16rn(float x) {   // RNE round to bf16 (low 16 bits)
    unsigned int u = __float_as_uint(x);
    u += 0x7fffu + ((u >> 16) & 1u);
    return u >> 16;
}
__device__ inline unsigned int pack2(float a, float b) {
    return bf16rn(a) | (bf16rn(b) << 16);
}
// 8 bf16 (uint4) -> 4 packed-f32 fma's into acc[0..3] (v_pk_fma_f32 path)
__device__ inline void bf8_fma2(float2v* acc, float w, uint4 hv) {
    const float2v wv = {w, w};
    float2v p0, p1, p2, p3;
    p0.x = __uint_as_float(hv.x << 16); p0.y = __uint_as_float(hv.x & 0xffff0000u);
    p1.x = __uint_as_float(hv.y << 16); p1.y = __uint_as_float(hv.y & 0xffff0000u);
    p2.x = __uint_as_float(hv.z << 16); p2.y = __uint_as_float(hv.z & 0xffff0000u);
    p3.x = __uint_as_float(hv.w << 16); p3.y = __uint_as_float(hv.w & 0xffff0000u);
    acc[0] += wv * p0;
    acc[1] += wv * p1;
    acc[2] += wv * p2;
    acc[3] += wv * p3;
}

// One-shot: pack W1 and W2 fp32 [128][128] into MFMA B-fragments (bf16).
// Also zeroes gscr (block 16) and cnt (block 16) — both written later.
__global__ void pack_wfrag2(const float* __restrict__ W1, const float* __restrict__ W2,
                            uint4* __restrict__ wf, float* __restrict__ gscr,
                            int* __restrict__ cnt) {
    const int p = blockIdx.x * blockDim.x + threadIdx.x;   // 0..4351
    if (p >= 4096) {                    // block 16: zero gscr + cnt
        const int t = threadIdx.x;
        for (int i = t; i < NG * 32; i += 256) gscr[i] = 0.f;
        for (int i = t; i < NBUCK; i += 256) cnt[i] = 0;
        return;
    }
    const float* W = (p < 2048) ? W1 : W2;
    const int q = p & 2047;
    const int f = q >> 6, l = q & 63;
    const int kt = f >> 3, nt = f & 7;
    const int rb = kt * 32 + ((l >> 4) << 3);
    const int col = nt * 16 + (l & 15);
    const float* wp = W + (size_t)rb * F + col;
    uint4 pk;
    pk.x = pack2(wp[0],     wp[F]);
    pk.y = pack2(wp[2 * F], wp[3 * F]);
    pk.z = pack2(wp[4 * F], wp[5 * F]);
    pk.w = pack2(wp[6 * F], wp[7 * F]);
    wf[p] = pk;
}

// gemm1 body: C[N,128] = x[N,128] @ W1 (fp32 A converted in-register) via
// v_mfma_f32_16x16x32_bf16, plus fused att_src/att_dst row projections.
__device__ __forceinline__ void gemm1_body(
        const float* __restrict__ Af, const uint4* __restrict__ wf,
        unsigned short* __restrict__ Cb,
        const float* __restrict__ att_src, const float* __restrict__ att_dst,
        float* __restrict__ asrc, float* __restrict__ adst, int bid) {
    const int t = threadIdx.x;
    const int wave = t >> 6, lane = t & 63;
    const int m0 = bid * 64 + wave * 16;
    const int arow = m0 + (lane & 15);
    const int kq = (lane >> 4) << 3;
    U8 a[4];
#pragma unroll
    for (int kt = 0; kt < 4; ++kt) {
        if (arow < NN) {
            const float* ap = Af + (size_t)arow * F + kt * 32 + kq;
            const float4 f0 = *(const float4*)ap;
            const float4 f1 = *(const float4*)(ap + 4);
            a[kt].u = make_uint4(pack2(f0.x, f0.y), pack2(f0.z, f0.w),
                                 pack2(f1.x, f1.y), pack2(f1.z, f1.w));
        } else {
            a[kt].u = make_uint4(0, 0, 0, 0);
        }
    }
    const int ccol = lane & 15;
    const int crow0 = m0 + ((lane >> 4) << 2);
    float ps[4] = {}, pd[4] = {};
    for (int nt = 0; nt < 8; nt += 2) {
        float4v acc0 = {0.f, 0.f, 0.f, 0.f}, acc1 = {0.f, 0.f, 0.f, 0.f};
#pragma unroll
        for (int kt = 0; kt < 4; ++kt) {
            U8 b0, b1;
            b0.u = wf[(kt * 8 + nt) * 64 + lane];
            b1.u = wf[(kt * 8 + nt + 1) * 64 + lane];
            acc0 = __builtin_amdgcn_mfma_f32_16x16x32_bf16(a[kt].s, b0.s, acc0, 0, 0, 0);
            acc1 = __builtin_amdgcn_mfma_f32_16x16x32_bf16(a[kt].s, b1.s, acc1, 0, 0, 0);
        }
#pragma unroll
        for (int r = 0; r < 4; ++r) {
            const int row = crow0 + r;
            if (row < NN) {
                Cb[(size_t)row * F + nt * 16 + ccol]       = (unsigned short)bf16rn(acc0[r]);
                Cb[(size_t)row * F + (nt + 1) * 16 + ccol] = (unsigned short)bf16rn(acc1[r]);
            }
        }
        const float as0 = att_src[nt * 16 + ccol], as1 = att_src[(nt + 1) * 16 + ccol];
        const float ad0 = att_dst[nt * 16 + ccol], ad1 = att_dst[(nt + 1) * 16 + ccol];
#pragma unroll
        for (int r = 0; r < 4; ++r) {
            ps[r] += acc0[r] * as0 + acc1[r] * as1;
            pd[r] += acc0[r] * ad0 + acc1[r] * ad1;
        }
    }
#pragma unroll
    for (int r = 0; r < 4; ++r) {
        float s = ps[r], d = pd[r];
#pragma unroll
        for (int o = 8; o; o >>= 1) { s += __shfl_xor(s, o); d += __shfl_xor(d, o); }
        const int row = crow0 + r;
        if (ccol == 0 && row < NN) { asrc[row] = s; adst[row] = d; }
    }
}

// ---- Fused: gemm1 (blocks [0,GB1)) + CSR bucket scatter (blocks [GB1,GB1+NBE)).
__global__ __launch_bounds__(256) void gemm1_count_scatter(
        const float* __restrict__ x, const uint4* __restrict__ wf1,
        unsigned short* __restrict__ h1b,
        const float* __restrict__ att_src, const float* __restrict__ att_dst,
        float* __restrict__ asrc, float* __restrict__ adst,
        const int* __restrict__ ei, int* __restrict__ cur,
        unsigned int* __restrict__ ebuf) {
    if (blockIdx.x < GB1) {
        gemm1_body(x, wf1, h1b, att_src, att_dst, asrc, adst, blockIdx.x);
        return;
    }
    __shared__ int lcnt[NBUCK];
    __shared__ int lbase[NBUCK];
    const int t = threadIdx.x, b = blockIdx.x - GB1;
    for (int i = t; i < NBUCK; i += 256) lcnt[i] = 0;
    __syncthreads();
    const int e0 = b * EPB;
    int sarr[EPB / 256], darr[EPB / 256];
#pragma unroll
    for (int i = 0; i < EPB / 256; ++i) {
        const int e = e0 + i * 256 + t;
        int s = 0, d = -1;
        if (e < EP) {
            if (e < NE) { s = ei[e]; d = ei[NE + e]; } else { s = d = e - NE; }
            atomicAdd(&lcnt[d >> 8], 1);
        }
        sarr[i] = s; darr[i] = d;
    }
    __syncthreads();
    for (int i = t; i < NBUCK; i += 256) {
        lbase[i] = atomicAdd(&cur[i], lcnt[i]);   // reserve contiguous run
        lcnt[i] = 0;                              // reuse as local cursor
    }
    __syncthreads();
#pragma unroll
    for (int i = 0; i < EPB / 256; ++i) {
        const int d = darr[i];
        if (d >= 0) {
            const int bk = d >> 8;
            const int p = lbase[bk] + atomicAdd(&lcnt[bk], 1);
            ebuf[(size_t)bk * BCAP + p] = (unsigned int)sarr[i] | ((unsigned int)(d & 255) << 16);
        }
    }
}

// ---- bucket_sort + edge softmax: per-bucket LDS counting sort, per-edge
// ev = exp(leaky(asrc[src]+adst[dst])) at the sorted position, per-node den
// (LDS-only serial sum over own run) -> inv_s, then a PARALLEL COALESCED
// emission pass writes both the pre-normalized (src, alpha) uint2 stream (GAT)
// and the compact 2B csr16 stream (GCN). dst8[] records the owning node per
// sorted slot so the emission loop is position-parallel.
__global__ __launch_bounds__(256) void bucket_sort(
        const unsigned int* __restrict__ ebuf, const int* __restrict__ cnt,
        const float* __restrict__ asrc, const float* __restrict__ adst,
        int* __restrict__ row_start, uint2* __restrict__ ca,
        unsigned short* __restrict__ csr16,
        int* __restrict__ deg, float* __restrict__ dinv) {
    __shared__ unsigned int earr[BCAP];            // 24K
    __shared__ float evarr[BCAP];                  // 24K
    __shared__ unsigned short out16[BCAP];         // 12K
    __shared__ unsigned char dst8[BCAP];           // 6K
    __shared__ int ecnt[256], epre[256];           // 2K
    __shared__ float adst_s[256];                  // 1K
    __shared__ float inv_s[256];                   // 1K
    const int t = threadIdx.x, g = blockIdx.x;
    const int m = cnt[g];
    const int n = g * 256 + t;
    adst_s[t] = (n < NN) ? adst[n] : 0.f;
    const unsigned int* src = ebuf + (size_t)g * BCAP;
    ecnt[t] = 0;
    __syncthreads();
    for (int i = t; i < m; i += 256) {
        const unsigned int v = src[i];
        earr[i] = v;
        atomicAdd(&ecnt[v >> 16], 1);
    }
    __syncthreads();
    const int v0 = ecnt[t];
    epre[t] = v0;
    __syncthreads();
    for (int o = 1; o < 256; o <<= 1) {
        const int u = (t >= o) ? epre[t - o] : 0;
        __syncthreads();
        epre[t] += u;
        __syncthreads();
    }
    const int my_excl = epre[t] - v0;
    if (n < NN) {
        row_start[n] = g * BCAP + my_excl;
        deg[n] = v0;                               // >= 1 (self loop)
        dinv[n] = rsqrtf((float)v0);
    }
    ecnt[t] = my_excl;
    __syncthreads();
#pragma unroll 4
    for (int i = t; i < m; i += 256) {             // sort scatter + edge score
        const unsigned int v = earr[i];
        const int s  = (int)(v & 0xffffu);
        const int dl = (int)(v >> 16);
        const int p  = atomicAdd(&ecnt[dl], 1);
        out16[p] = (unsigned short)s;
        dst8[p]  = (unsigned char)dl;
        float sc = asrc[s] + adst_s[dl];
        sc = sc > 0.f ? sc : 0.2f * sc;
        evarr[p] = __expf(sc);
    }
    __syncthreads();
    {   // per-node den over own run (LDS-only; ~deg iterations)
        float den = 0.f;
        for (int k = 0; k < v0; ++k) den += evarr[my_excl + k];
        inv_s[t] = (v0 > 0) ? (1.f / den) : 0.f;   // den > 0 (self loop)
    }
    __syncthreads();
    uint2* cap = ca + (size_t)g * BCAP;
    unsigned short* c16 = csr16 + (size_t)g * BCAP;
    for (int i = t; i < m; i += 256) {             // coalesced emission
        const unsigned short s = out16[i];
        const float a = evarr[i] * inv_s[dst8[i]];
        cap[i] = make_uint2((unsigned int)s, __float_as_uint(a));
        c16[i] = s;
    }
}

// ---- GAT gather fused with gemm2: quarter-per-node gather (16 lanes/node,
// 16 nodes/block, grid exact NN/16). Weights are pre-normalized alphas from
// the ca stream — single sequential 8B load per edge, shfl broadcast, row
// load, FMA. Then the block's 16 rows form one MFMA 16x16 A-tile: stage
// post-ReLU bf16 rows in LDS (pad 17), barrier, each wave computes 2
// nt-columns of h2 = h_gat @ W2, scales by dinv[node], stores h2b.
__global__ __launch_bounds__(256) void gat_gemm2(
        const int* __restrict__ row_start, const int* __restrict__ deg,
        const uint2* __restrict__ ca,
        const unsigned short* __restrict__ hb, const float* __restrict__ bias,
        const uint4* __restrict__ wf2, const float* __restrict__ dinv,
        unsigned short* __restrict__ h2b) {
    __shared__ uint4 ldsA[16][17];                  // 16 nodes x 128 bf16, pad 17
    const int lane = threadIdx.x & 63;
    const int qid  = threadIdx.x >> 4;              // 0..15: node slot in block
    const int n    = blockIdx.x * 16 + qid;         // grid exact: 3125*16 = 50000
    const int lanesub = lane & 15;
    const int qb   = lane & 48;                     // quarter base lane
    const int qo   = lanesub << 3;                  // 8 channels per lane
    const int lo = row_start[n], hi = lo + deg[n];
    float2v acc[4];
#pragma unroll
    for (int i = 0; i < 4; ++i) acc[i] = (float2v){0.f, 0.f};
    for (int base = lo; base < hi; base += 16) {
        const int cnt = min(16, hi - base);
        int sv = 0; float ev = 0.f;
        if (lanesub < cnt) {
            const uint2 e = ca[base + lanesub];
            sv = (int)e.x; ev = __uint_as_float(e.y);
        }
        for (int j = 0; j < cnt; j += 8) {          // slots past cnt have ev=0
            int ss[8]; float ww[8]; uint4 hh[8];
#pragma unroll
            for (int k = 0; k < 8; ++k) {
                ss[k] = __shfl(sv, qb + j + k);
                ww[k] = __shfl(ev, qb + j + k);
            }
#pragma unroll
            for (int k = 0; k < 8; ++k)
                hh[k] = *(const uint4*)(hb + (size_t)ss[k] * F + qo);
#pragma unroll
            for (int k = 0; k < 8; ++k) bf8_fma2(acc, ww[k], hh[k]);
        }
    }
    const float4 b0 = *(const float4*)(bias + qo);
    const float4 b1 = *(const float4*)(bias + qo + 4);
    float v[8];
    v[0] = acc[0].x + b0.x; v[1] = acc[0].y + b0.y;
    v[2] = acc[1].x + b0.z; v[3] = acc[1].y + b0.w;
    v[4] = acc[2].x + b1.x; v[5] = acc[2].y + b1.y;
    v[6] = acc[3].x + b1.z; v[7] = acc[3].y + b1.w;
#pragma unroll
    for (int i = 0; i < 8; ++i) v[i] = v[i] > 0.f ? v[i] : 0.f;
    uint4 pk;
    pk.x = pack2(v[0], v[1]); pk.y = pack2(v[2], v[3]);
    pk.z = pack2(v[4], v[5]); pk.w = pack2(v[6], v[7]);
    ldsA[qid][lanesub] = pk;
    __syncthreads();
    // ---- gemm2 phase: wave w computes nt = 2w, 2w+1
    const int wave = threadIdx.x >> 6;
    U8 a[4];
#pragma unroll
    for (int kt = 0; kt < 4; ++kt)
        a[kt].u = ldsA[lane & 15][kt * 4 + (lane >> 4)];
    const int nt = wave * 2;
    float4v acc0 = {0.f, 0.f, 0.f, 0.f}, acc1 = {0.f, 0.f, 0.f, 0.f};
#pragma unroll
    for (int kt = 0; kt < 4; ++kt) {
        U8 b0f, b1f;
        b0f.u = wf2[(kt * 8 + nt) * 64 + lane];
        b1f.u = wf2[(kt * 8 + nt + 1) * 64 + lane];
        acc0 = __builtin_amdgcn_mfma_f32_16x16x32_bf16(a[kt].s, b0f.s, acc0, 0, 0, 0);
        acc1 = __builtin_amdgcn_mfma_f32_16x16x32_bf16(a[kt].s, b1f.s, acc1, 0, 0, 0);
    }
    const int ccol = lane & 15;
    const int crow0 = (lane >> 4) << 2;
#pragma unroll
    for (int r = 0; r < 4; ++r) {
        const int node = blockIdx.x * 16 + crow0 + r;
        const float rs = dinv[node];
        h2b[(size_t)node * F + nt * 16 + ccol]       = (unsigned short)bf16rn(acc0[r] * rs);
        h2b[(size_t)node * F + (nt + 1) * 16 + ccol] = (unsigned short)bf16rn(acc1[r] * rs);
    }
}

// ---- GCN gather + pool, quarter-per-node (pre-scaled h2 rows; compact 2B
// csr16 edge stream; tail slots predicated with w=0, a quarter-uniform test).
__global__ __launch_bounds__(256) void gcn_gather_pool(
        const int* __restrict__ row_start, const int* __restrict__ deg,
        const unsigned short* __restrict__ csr_src,
        const float* __restrict__ dinv, const unsigned short* __restrict__ hb,
        const float* __restrict__ bias, const int* __restrict__ batch,
        const float* __restrict__ Wf, float* __restrict__ gscr) {
    __shared__ int   sg[16];
    __shared__ float sp0[16], sp1[16];
    const int lane = threadIdx.x & 63;
    const int qid  = threadIdx.x >> 4;
    const int n    = blockIdx.x * 16 + qid;
    const int lanesub = lane & 15;
    const int qb   = lane & 48;
    const int qo   = lanesub << 3;
    const int lo = row_start[n], hi = lo + deg[n];
    const float dn = dinv[n];
    float2v acc[4];
#pragma unroll
    for (int i = 0; i < 4; ++i) acc[i] = (float2v){0.f, 0.f};
    for (int base = lo; base < hi; base += 16) {
        const int cnt = min(16, hi - base);
        int sv = 0;
        if (lanesub < cnt) sv = (int)csr_src[base + lanesub];
        for (int j = 0; j < cnt; j += 8) {
            int ss[8]; uint4 hh[8];
#pragma unroll
            for (int k = 0; k < 8; ++k) ss[k] = __shfl(sv, qb + j + k);
#pragma unroll
            for (int k = 0; k < 8; ++k)
                hh[k] = *(const uint4*)(hb + (size_t)ss[k] * F + qo);
#pragma unroll
            for (int k = 0; k < 8; ++k) {
                const float w = (j + k < cnt) ? 1.f : 0.f;   // quarter-uniform
                bf8_fma2(acc, w, hh[k]);
            }
        }
    }
    const float4 b0 = *(const float4*)(bias + qo);
    const float4 b1 = *(const float4*)(bias + qo + 4);
    float v[8];
    v[0] = fmaf(acc[0].x, dn, b0.x); v[1] = fmaf(acc[0].y, dn, b0.y);
    v[2] = fmaf(acc[1].x, dn, b0.z); v[3] = fmaf(acc[1].y, dn, b0.w);
    v[4] = fmaf(acc[2].x, dn, b1.x); v[5] = fmaf(acc[2].y, dn, b1.y);
    v[6] = fmaf(acc[3].x, dn, b1.z); v[7] = fmaf(acc[3].y, dn, b1.w);
#pragma unroll
    for (int i = 0; i < 8; ++i) v[i] = v[i] > 0.f ? v[i] : 0.f;
    const float4 w0 = *(const float4*)(Wf + qo * 2);
    const float4 w1 = *(const float4*)(Wf + qo * 2 + 4);
    const float4 w2 = *(const float4*)(Wf + qo * 2 + 8);
    const float4 w3 = *(const float4*)(Wf + qo * 2 + 12);
    float p0 = v[0]*w0.x + v[1]*w0.z + v[2]*w1.x + v[3]*w1.z +
               v[4]*w2.x + v[5]*w2.z + v[6]*w3.x + v[7]*w3.z;
    float p1 = v[0]*w0.y + v[1]*w0.w + v[2]*w1.y + v[3]*w1.w +
               v[4]*w2.y + v[5]*w2.w + v[6]*w3.y + v[7]*w3.w;
#pragma unroll
    for (int o = 8; o; o >>= 1) { p0 += __shfl_xor(p0, o); p1 += __shfl_xor(p1, o); }
    if (lanesub == 0) { sg[qid] = batch[n]; sp0[qid] = p0; sp1[qid] = p1; }
    __syncthreads();
    if (threadIdx.x == 0) {
#pragma unroll 1
        for (int w = 0; w < 16; ++w) {
            const int g = sg[w];
            if (g < 0) continue;
            float q0 = sp0[w], q1 = sp1[w];
            for (int u = w + 1; u < 16; ++u) {
                if (sg[u] == g) { q0 += sp0[u]; q1 += sp1[u]; sg[u] = -1; }
            }
            atomicAdd(gscr + g * 32,     q0);
            atomicAdd(gscr + g * 32 + 1, q1);
        }
    }
}

__global__ void finalize(const float* __restrict__ gscr, const int* __restrict__ batch,
                         const float* __restrict__ bf, float* __restrict__ out) {
    const int g = threadIdx.x;   // 128
    int lo = 0, hi = NN;
    while (lo < hi) { int m = (lo + hi) >> 1; if (batch[m] < g) lo = m + 1; else hi = m; }
    int lo2 = lo, hi2 = NN;
    while (lo2 < hi2) { int m = (lo2 + hi2) >> 1; if (batch[m] < g + 1) lo2 = m + 1; else hi2 = m; }
    const float inv = 1.f / fmaxf((float)(lo2 - lo), 1.f);
    out[g * 2]     = gscr[g * 32]     * inv + bf[0];
    out[g * 2 + 1] = gscr[g * 32 + 1] * inv + bf[1];
}

extern "C" void kernel_launch(void* const* d_in, const int* in_sizes, int n_in,
                              void* d_out, int out_size, void* d_ws, size_t ws_size,
                              hipStream_t stream) {
    const float* x       = (const float*)d_in[0];
    const float* W1      = (const float*)d_in[1];
    const float* att_src = (const float*)d_in[2];
    const float* att_dst = (const float*)d_in[3];
    const float* b1      = (const float*)d_in[4];
    const float* W2      = (const float*)d_in[5];
    const float* b2      = (const float*)d_in[6];
    const float* Wf      = (const float*)d_in[7];
    const float* bf      = (const float*)d_in[8];
    const int*   ei      = (const int*)d_in[9];
    const int*   batch   = (const int*)d_in[10];
    float* out = (float*)d_out;

    // layout: descending alignment
    uint4* wf1       = (uint4*)d_ws;                                // [2048] W1 frags (32 KB)
    uint4* wf2       = wf1 + 2048;                                  // [2048] W2 frags (32 KB)
    uint2* ca        = (uint2*)(wf2 + 2048);                        // [NBUCK*BCAP] (src, alpha)
    unsigned int* ebuf = (unsigned int*)(ca + (size_t)NBUCK * BCAP);// [NBUCK*BCAP]
    unsigned short* h1b = (unsigned short*)(ebuf + (size_t)NBUCK * BCAP); // [NN*F] bf16
    unsigned short* h2b = h1b + (size_t)NN * F;                     // [NN*F] bf16 pre-scaled
    unsigned short* csr16 = h2b + (size_t)NN * F;                   // [NBUCK*BCAP] 2B src
    float* asrc      = (float*)(csr16 + (size_t)NBUCK * BCAP);      // [NN]
    float* adst      = asrc + NN;                                   // [NN]
    float* dinv      = adst + NN;                                   // [NN]
    float* gscr      = dinv + NN;                                   // [NG*32]
    int*   row_start = (int*)(gscr + NG * 32);                      // [NN]
    int*   deg       = row_start + NN;                              // [NN]
    int*   cnt       = deg + NN;                                    // [NBUCK]

    // one-shot weight packing (+ gscr/cnt zeroing)
    pack_wfrag2<<<17, 256, 0, stream>>>(W1, W2, wf1, gscr, cnt);
    // gemm1 and CSR scatter are independent: one fused dispatch
    gemm1_count_scatter<<<GB1 + NBE, 256, 0, stream>>>(x, wf1, h1b, att_src, att_dst,
                                                       asrc, adst, ei, cnt, ebuf);
    bucket_sort<<<NBUCK, 256, 0, stream>>>(ebuf, cnt, asrc, adst,
                                           row_start, ca, csr16, deg, dinv);
    gat_gemm2<<<NN / 16, 256, 0, stream>>>(row_start, deg, ca, h1b, b1, wf2, dinv, h2b);
    gcn_gather_pool<<<NN / 16, 256, 0, stream>>>(row_start, deg, csr16, dinv, h2b, b2,
                                                 batch, Wf, gscr);
    finalize<<<1, NG, 0, stream>>>(gscr, batch, bf, out);
}

// Round 5
// 171.600 us; speedup vs baseline: 1.1336x; 1.1101x over previous
//
#include <hip/hip_runtime.h>

#define NN 50000
#define NE 800000
#define EP (NE + NN)      // edges + self loops = 850000
#define NG 128
#define F 128
#define NBE 208           // edge-pass blocks
#define EPB 4096          // edges per block (208*4096 >= EP)
#define NBUCK 196         // dst buckets of 256 nodes
#define BCAP 6144         // per-bucket edge cap (mean 4352, max ~4650)
#define GB1 782           // gemm1 blocks: (NN+63)/64

typedef __attribute__((ext_vector_type(8))) short short8;
typedef __attribute__((ext_vector_type(4))) float float4v;
typedef __attribute__((ext_vector_type(2))) float float2v;
union U8 { uint4 u; short8 s; };

__device__ inline unsigned int bf16rn(float x) {   // RNE round to bf16 (low 16 bits)
    unsigned int u = __float_as_uint(x);
    u += 0x7fffu + ((u >> 16) & 1u);
    return u >> 16;
}
__device__ inline unsigned int pack2(float a, float b) {
    return bf16rn(a) | (bf16rn(b) << 16);
}
// 8 fp8-e4m3 (uint2, storage order) -> 4 packed-f32 fma's into acc[0..3].
// Storage byte b of a row = logical channel b*16 + lane's group col; the
// permutation is consistent across producer/consumer so no reshuffle needed.
__device__ inline void fp8_fma2(float2v* acc, float w, uint2 hv) {
    const float2v wv = {w, w};
    float2v p0 = __builtin_amdgcn_cvt_pk_f32_fp8((int)hv.x, false);
    float2v p1 = __builtin_amdgcn_cvt_pk_f32_fp8((int)hv.x, true);
    float2v p2 = __builtin_amdgcn_cvt_pk_f32_fp8((int)hv.y, false);
    float2v p3 = __builtin_amdgcn_cvt_pk_f32_fp8((int)hv.y, true);
    acc[0] += wv * p0;
    acc[1] += wv * p1;
    acc[2] += wv * p2;
    acc[3] += wv * p3;
}

// One-shot: pack W1 and W2 fp32 [128][128] into MFMA B-fragments (bf16).
// W2's K-rows are PERMUTED to the fp8 storage order (storage k: logical row
// = (k&7)*16 + (k>>3)) so gemm2 consumes the permuted A-tiles unchanged.
// Also zeroes gscr (block 16) and cnt (block 16) — both written later.
__global__ void pack_wfrag2(const float* __restrict__ W1, const float* __restrict__ W2,
                            uint4* __restrict__ wf, float* __restrict__ gscr,
                            int* __restrict__ cnt) {
    const int p = blockIdx.x * blockDim.x + threadIdx.x;   // 0..4351
    if (p >= 4096) {                    // block 16: zero gscr + cnt
        const int t = threadIdx.x;
        for (int i = t; i < NG * 32; i += 256) gscr[i] = 0.f;
        for (int i = t; i < NBUCK; i += 256) cnt[i] = 0;
        return;
    }
    const int q = p & 2047;
    const int f = q >> 6, l = q & 63;
    const int kt = f >> 3, nt = f & 7;
    const int rb = kt * 32 + ((l >> 4) << 3);
    const int col = nt * 16 + (l & 15);
    uint4 pk;
    if (p < 2048) {                     // W1: natural K order (A = x, fp32)
        const float* wp = W1 + (size_t)rb * F + col;
        pk.x = pack2(wp[0],     wp[F]);
        pk.y = pack2(wp[2 * F], wp[3 * F]);
        pk.z = pack2(wp[4 * F], wp[5 * F]);
        pk.w = pack2(wp[6 * F], wp[7 * F]);
    } else {                            // W2: permuted K (storage order)
        const int rbs = rb >> 3;
        const float* wp = W2 + (size_t)rbs * F + col;   // row j*16 + rbs
        pk.x = pack2(wp[(size_t)0 * 16 * F], wp[(size_t)1 * 16 * F]);
        pk.y = pack2(wp[(size_t)2 * 16 * F], wp[(size_t)3 * 16 * F]);
        pk.z = pack2(wp[(size_t)4 * 16 * F], wp[(size_t)5 * 16 * F]);
        pk.w = pack2(wp[(size_t)6 * 16 * F], wp[(size_t)7 * 16 * F]);
    }
    wf[p] = pk;
}

// gemm1 body: C[N,128] = x[N,128] @ W1 via v_mfma_f32_16x16x32_bf16, plus
// fused att_src/att_dst row projections. Epilogue packs each row's 8 output
// bytes (fp8 e4m3, storage order: byte ccol*8+nt = logical ch nt*16+ccol)
// into ONE uint2 store per row — 4 stores/thread vs 64 2B stores.
__device__ __forceinline__ void gemm1_body(
        const float* __restrict__ Af, const uint4* __restrict__ wf,
        uint2* __restrict__ Cb8,
        const float* __restrict__ att_src, const float* __restrict__ att_dst,
        float* __restrict__ asrc, float* __restrict__ adst, int bid) {
    const int t = threadIdx.x;
    const int wave = t >> 6, lane = t & 63;
    const int m0 = bid * 64 + wave * 16;
    const int arow = m0 + (lane & 15);
    const int kq = (lane >> 4) << 3;
    U8 a[4];
#pragma unroll
    for (int kt = 0; kt < 4; ++kt) {
        if (arow < NN) {
            const float* ap = Af + (size_t)arow * F + kt * 32 + kq;
            const float4 f0 = *(const float4*)ap;
            const float4 f1 = *(const float4*)(ap + 4);
            a[kt].u = make_uint4(pack2(f0.x, f0.y), pack2(f0.z, f0.w),
                                 pack2(f1.x, f1.y), pack2(f1.z, f1.w));
        } else {
            a[kt].u = make_uint4(0, 0, 0, 0);
        }
    }
    const int ccol = lane & 15;
    const int crow0 = m0 + ((lane >> 4) << 2);
    float ps[4] = {}, pd[4] = {};
    int plo[4] = {0, 0, 0, 0}, phi[4] = {0, 0, 0, 0};
#pragma unroll
    for (int ntp = 0; ntp < 4; ++ntp) {
        const int nt = ntp * 2;
        float4v acc0 = {0.f, 0.f, 0.f, 0.f}, acc1 = {0.f, 0.f, 0.f, 0.f};
#pragma unroll
        for (int kt = 0; kt < 4; ++kt) {
            U8 b0, b1;
            b0.u = wf[(kt * 8 + nt) * 64 + lane];
            b1.u = wf[(kt * 8 + nt + 1) * 64 + lane];
            acc0 = __builtin_amdgcn_mfma_f32_16x16x32_bf16(a[kt].s, b0.s, acc0, 0, 0, 0);
            acc1 = __builtin_amdgcn_mfma_f32_16x16x32_bf16(a[kt].s, b1.s, acc1, 0, 0, 0);
        }
#pragma unroll
        for (int r = 0; r < 4; ++r) {
            if (ntp == 0)      plo[r] = __builtin_amdgcn_cvt_pk_fp8_f32(acc0[r], acc1[r], plo[r], false);
            else if (ntp == 1) plo[r] = __builtin_amdgcn_cvt_pk_fp8_f32(acc0[r], acc1[r], plo[r], true);
            else if (ntp == 2) phi[r] = __builtin_amdgcn_cvt_pk_fp8_f32(acc0[r], acc1[r], phi[r], false);
            else               phi[r] = __builtin_amdgcn_cvt_pk_fp8_f32(acc0[r], acc1[r], phi[r], true);
        }
        const float as0 = att_src[nt * 16 + ccol], as1 = att_src[(nt + 1) * 16 + ccol];
        const float ad0 = att_dst[nt * 16 + ccol], ad1 = att_dst[(nt + 1) * 16 + ccol];
#pragma unroll
        for (int r = 0; r < 4; ++r) {
            ps[r] += acc0[r] * as0 + acc1[r] * as1;
            pd[r] += acc0[r] * ad0 + acc1[r] * ad1;
        }
    }
#pragma unroll
    for (int r = 0; r < 4; ++r) {
        const int row = crow0 + r;
        if (row < NN)
            Cb8[(size_t)row * 16 + ccol] = make_uint2((unsigned)plo[r], (unsigned)phi[r]);
    }
#pragma unroll
    for (int r = 0; r < 4; ++r) {
        float s = ps[r], d = pd[r];
#pragma unroll
        for (int o = 8; o; o >>= 1) { s += __shfl_xor(s, o); d += __shfl_xor(d, o); }
        const int row = crow0 + r;
        if (ccol == 0 && row < NN) { asrc[row] = s; adst[row] = d; }
    }
}

// ---- Fused: gemm1 (blocks [0,GB1)) + CSR bucket scatter (blocks [GB1,GB1+NBE)).
__global__ __launch_bounds__(256) void gemm1_count_scatter(
        const float* __restrict__ x, const uint4* __restrict__ wf1,
        uint2* __restrict__ h1b,
        const float* __restrict__ att_src, const float* __restrict__ att_dst,
        float* __restrict__ asrc, float* __restrict__ adst,
        const int* __restrict__ ei, int* __restrict__ cur,
        unsigned int* __restrict__ ebuf) {
    if (blockIdx.x < GB1) {
        gemm1_body(x, wf1, h1b, att_src, att_dst, asrc, adst, blockIdx.x);
        return;
    }
    __shared__ int lcnt[NBUCK];
    __shared__ int lbase[NBUCK];
    const int t = threadIdx.x, b = blockIdx.x - GB1;
    for (int i = t; i < NBUCK; i += 256) lcnt[i] = 0;
    __syncthreads();
    const int e0 = b * EPB;
    int sarr[EPB / 256], darr[EPB / 256];
#pragma unroll
    for (int i = 0; i < EPB / 256; ++i) {
        const int e = e0 + i * 256 + t;
        int s = 0, d = -1;
        if (e < EP) {
            if (e < NE) { s = ei[e]; d = ei[NE + e]; } else { s = d = e - NE; }
            atomicAdd(&lcnt[d >> 8], 1);
        }
        sarr[i] = s; darr[i] = d;
    }
    __syncthreads();
    for (int i = t; i < NBUCK; i += 256) {
        lbase[i] = atomicAdd(&cur[i], lcnt[i]);   // reserve contiguous run
        lcnt[i] = 0;                              // reuse as local cursor
    }
    __syncthreads();
#pragma unroll
    for (int i = 0; i < EPB / 256; ++i) {
        const int d = darr[i];
        if (d >= 0) {
            const int bk = d >> 8;
            const int p = lbase[bk] + atomicAdd(&lcnt[bk], 1);
            ebuf[(size_t)bk * BCAP + p] = (unsigned int)sarr[i] | ((unsigned int)(d & 255) << 16);
        }
    }
}

// ---- bucket_sort + edge softmax (unchanged from r4): LDS counting sort,
// per-edge ev at sorted position, per-node den -> inv, parallel coalesced
// emission of (src, alpha) uint2 (GAT) and 2B csr16 (GCN).
__global__ __launch_bounds__(256) void bucket_sort(
        const unsigned int* __restrict__ ebuf, const int* __restrict__ cnt,
        const float* __restrict__ asrc, const float* __restrict__ adst,
        int* __restrict__ row_start, uint2* __restrict__ ca,
        unsigned short* __restrict__ csr16,
        int* __restrict__ deg, float* __restrict__ dinv) {
    __shared__ unsigned int earr[BCAP];            // 24K
    __shared__ float evarr[BCAP];                  // 24K
    __shared__ unsigned short out16[BCAP];         // 12K
    __shared__ unsigned char dst8[BCAP];           // 6K
    __shared__ int ecnt[256], epre[256];           // 2K
    __shared__ float adst_s[256];                  // 1K
    __shared__ float inv_s[256];                   // 1K
    const int t = threadIdx.x, g = blockIdx.x;
    const int m = cnt[g];
    const int n = g * 256 + t;
    adst_s[t] = (n < NN) ? adst[n] : 0.f;
    const unsigned int* src = ebuf + (size_t)g * BCAP;
    ecnt[t] = 0;
    __syncthreads();
    for (int i = t; i < m; i += 256) {
        const unsigned int v = src[i];
        earr[i] = v;
        atomicAdd(&ecnt[v >> 16], 1);
    }
    __syncthreads();
    const int v0 = ecnt[t];
    epre[t] = v0;
    __syncthreads();
    for (int o = 1; o < 256; o <<= 1) {
        const int u = (t >= o) ? epre[t - o] : 0;
        __syncthreads();
        epre[t] += u;
        __syncthreads();
    }
    const int my_excl = epre[t] - v0;
    if (n < NN) {
        row_start[n] = g * BCAP + my_excl;
        deg[n] = v0;                               // >= 1 (self loop)
        dinv[n] = rsqrtf((float)v0);
    }
    ecnt[t] = my_excl;
    __syncthreads();
#pragma unroll 4
    for (int i = t; i < m; i += 256) {             // sort scatter + edge score
        const unsigned int v = earr[i];
        const int s  = (int)(v & 0xffffu);
        const int dl = (int)(v >> 16);
        const int p  = atomicAdd(&ecnt[dl], 1);
        out16[p] = (unsigned short)s;
        dst8[p]  = (unsigned char)dl;
        float sc = asrc[s] + adst_s[dl];
        sc = sc > 0.f ? sc : 0.2f * sc;
        evarr[p] = __expf(sc);
    }
    __syncthreads();
    {   // per-node den over own run (LDS-only; ~deg iterations)
        float den = 0.f;
        for (int k = 0; k < v0; ++k) den += evarr[my_excl + k];
        inv_s[t] = (v0 > 0) ? (1.f / den) : 0.f;   // den > 0 (self loop)
    }
    __syncthreads();
    uint2* cap = ca + (size_t)g * BCAP;
    unsigned short* c16 = csr16 + (size_t)g * BCAP;
    for (int i = t; i < m; i += 256) {             // coalesced emission
        const unsigned short s = out16[i];
        const float a = evarr[i] * inv_s[dst8[i]];
        cap[i] = make_uint2((unsigned int)s, __float_as_uint(a));
        c16[i] = s;
    }
}

// ---- GAT gather (fp8 rows, 1 line/edge) fused with gemm2.
// Quarter-per-node: 16 lanes/node, lane owns 8 storage bytes (= logical
// channels j*16+lanesub). Chunk of 16 edges: BOTH 8-groups' row loads are
// issued before any FMA (16 lines in flight/quarter — same line-level
// concurrency as the bf16 version at half the bytes).
__global__ __launch_bounds__(256) void gat_gemm2(
        const int* __restrict__ row_start, const int* __restrict__ deg,
        const uint2* __restrict__ ca,
        const unsigned char* __restrict__ hb, const float* __restrict__ bias,
        const uint4* __restrict__ wf2, const float* __restrict__ dinv,
        unsigned char* __restrict__ h2b) {
    __shared__ uint4 ldsA[16][17];                  // 16 nodes x 128 bf16, pad 17
    const int lane = threadIdx.x & 63;
    const int qid  = threadIdx.x >> 4;              // 0..15: node slot in block
    const int n    = blockIdx.x * 16 + qid;         // grid exact: 3125*16 = 50000
    const int lanesub = lane & 15;
    const int qb   = lane & 48;                     // quarter base lane
    const int qo8  = lanesub << 3;                  // 8 storage bytes per lane
    const int lo = row_start[n], hi = lo + deg[n];
    float2v acc[4];
#pragma unroll
    for (int i = 0; i < 4; ++i) acc[i] = (float2v){0.f, 0.f};
    for (int base = lo; base < hi; base += 16) {
        const int cnt = min(16, hi - base);
        int sv = 0; float ev = 0.f;
        if (lanesub < cnt) {
            const uint2 e = ca[base + lanesub];
            sv = (int)e.x; ev = __uint_as_float(e.y);
        }
        int ss0[8]; float ww0[8]; uint2 hh0[8], hh1[8];
#pragma unroll
        for (int k = 0; k < 8; ++k) {
            ss0[k] = __shfl(sv, qb + k);
            ww0[k] = __shfl(ev, qb + k);
        }
#pragma unroll
        for (int k = 0; k < 8; ++k)
            hh0[k] = *(const uint2*)(hb + (size_t)ss0[k] * F + qo8);
        const bool g1 = cnt > 8;                    // quarter-uniform
        float ww1[8];
        if (g1) {
            int ss1[8];
#pragma unroll
            for (int k = 0; k < 8; ++k) {
                ss1[k] = __shfl(sv, qb + 8 + k);
                ww1[k] = __shfl(ev, qb + 8 + k);
            }
#pragma unroll
            for (int k = 0; k < 8; ++k)
                hh1[k] = *(const uint2*)(hb + (size_t)ss1[k] * F + qo8);
        }
#pragma unroll
        for (int k = 0; k < 8; ++k) fp8_fma2(acc, ww0[k], hh0[k]);
        if (g1) {
#pragma unroll
            for (int k = 0; k < 8; ++k) fp8_fma2(acc, ww1[k], hh1[k]);
        }
    }
    float v[8];
#pragma unroll
    for (int j = 0; j < 4; ++j) { v[2 * j] = acc[j].x; v[2 * j + 1] = acc[j].y; }
#pragma unroll
    for (int j = 0; j < 8; ++j) {
        const float tv = v[j] + bias[j * 16 + lanesub];   // logical ch j*16+ls
        v[j] = tv > 0.f ? tv : 0.f;
    }
    uint4 pk;
    pk.x = pack2(v[0], v[1]); pk.y = pack2(v[2], v[3]);
    pk.z = pack2(v[4], v[5]); pk.w = pack2(v[6], v[7]);
    ldsA[qid][lanesub] = pk;                        // storage-k order bf16
    __syncthreads();
    // ---- gemm2 phase: wave w computes nt = 2w, 2w+1 (wf2 K pre-permuted)
    const int wave = threadIdx.x >> 6;
    U8 a[4];
#pragma unroll
    for (int kt = 0; kt < 4; ++kt)
        a[kt].u = ldsA[lane & 15][kt * 4 + (lane >> 4)];
    const int nt = wave * 2;
    float4v acc0 = {0.f, 0.f, 0.f, 0.f}, acc1 = {0.f, 0.f, 0.f, 0.f};
#pragma unroll
    for (int kt = 0; kt < 4; ++kt) {
        U8 b0f, b1f;
        b0f.u = wf2[(kt * 8 + nt) * 64 + lane];
        b1f.u = wf2[(kt * 8 + nt + 1) * 64 + lane];
        acc0 = __builtin_amdgcn_mfma_f32_16x16x32_bf16(a[kt].s, b0f.s, acc0, 0, 0, 0);
        acc1 = __builtin_amdgcn_mfma_f32_16x16x32_bf16(a[kt].s, b1f.s, acc1, 0, 0, 0);
    }
    const int ccol = lane & 15;
    const int crow0 = (lane >> 4) << 2;
#pragma unroll
    for (int r = 0; r < 4; ++r) {
        const int node = blockIdx.x * 16 + crow0 + r;
        const float rs = dinv[node];
        const int pk8 = __builtin_amdgcn_cvt_pk_fp8_f32(acc0[r] * rs, acc1[r] * rs, 0, false);
        // storage bytes (ccol*8+nt, ccol*8+nt+1) = logical ch (nt*16+ccol, ..)
        *(unsigned short*)(h2b + (size_t)node * F + ccol * 8 + nt) = (unsigned short)pk8;
    }
}

// ---- GCN gather + pool (fp8 pre-scaled h2 rows, 2B csr16 edge stream).
__global__ __launch_bounds__(256) void gcn_gather_pool(
        const int* __restrict__ row_start, const int* __restrict__ deg,
        const unsigned short* __restrict__ csr_src,
        const float* __restrict__ dinv, const unsigned char* __restrict__ hb,
        const float* __restrict__ bias, const int* __restrict__ batch,
        const float* __restrict__ Wf, float* __restrict__ gscr) {
    __shared__ int   sg[16];
    __shared__ float sp0[16], sp1[16];
    const int lane = threadIdx.x & 63;
    const int qid  = threadIdx.x >> 4;
    const int n    = blockIdx.x * 16 + qid;
    const int lanesub = lane & 15;
    const int qb   = lane & 48;
    const int qo8  = lanesub << 3;
    const int lo = row_start[n], hi = lo + deg[n];
    const float dn = dinv[n];
    float2v acc[4];
#pragma unroll
    for (int i = 0; i < 4; ++i) acc[i] = (float2v){0.f, 0.f};
    for (int base = lo; base < hi; base += 16) {
        const int cnt = min(16, hi - base);
        int sv = 0;
        if (lanesub < cnt) sv = (int)csr_src[base + lanesub];
        int ss0[8]; uint2 hh0[8], hh1[8];
#pragma unroll
        for (int k = 0; k < 8; ++k) ss0[k] = __shfl(sv, qb + k);
#pragma unroll
        for (int k = 0; k < 8; ++k)
            hh0[k] = *(const uint2*)(hb + (size_t)ss0[k] * F + qo8);
        const bool g1 = cnt > 8;                    // quarter-uniform
        if (g1) {
            int ss1[8];
#pragma unroll
            for (int k = 0; k < 8; ++k) ss1[k] = __shfl(sv, qb + 8 + k);
#pragma unroll
            for (int k = 0; k < 8; ++k)
                hh1[k] = *(const uint2*)(hb + (size_t)ss1[k] * F + qo8);
        }
#pragma unroll
        for (int k = 0; k < 8; ++k)
            fp8_fma2(acc, (k < cnt) ? 1.f : 0.f, hh0[k]);
        if (g1) {
#pragma unroll
            for (int k = 0; k < 8; ++k)
                fp8_fma2(acc, (8 + k < cnt) ? 1.f : 0.f, hh1[k]);
        }
    }
    float v[8];
#pragma unroll
    for (int j = 0; j < 4; ++j) { v[2 * j] = acc[j].x; v[2 * j + 1] = acc[j].y; }
    float p0 = 0.f, p1 = 0.f;
#pragma unroll
    for (int j = 0; j < 8; ++j) {
        const int ch = j * 16 + lanesub;            // logical channel
        float tv = fmaf(v[j], dn, bias[ch]);
        tv = tv > 0.f ? tv : 0.f;
        const float2 wv = *(const float2*)(Wf + (ch << 1));
        p0 += tv * wv.x;
        p1 += tv * wv.y;
    }
#pragma unroll
    for (int o = 8; o; o >>= 1) { p0 += __shfl_xor(p0, o); p1 += __shfl_xor(p1, o); }
    if (lanesub == 0) { sg[qid] = batch[n]; sp0[qid] = p0; sp1[qid] = p1; }
    __syncthreads();
    if (threadIdx.x == 0) {
#pragma unroll 1
        for (int w = 0; w < 16; ++w) {
            const int g = sg[w];
            if (g < 0) continue;
            float q0 = sp0[w], q1 = sp1[w];
            for (int u = w + 1; u < 16; ++u) {
                if (sg[u] == g) { q0 += sp0[u]; q1 += sp1[u]; sg[u] = -1; }
            }
            atomicAdd(gscr + g * 32,     q0);
            atomicAdd(gscr + g * 32 + 1, q1);
        }
    }
}

__global__ void finalize(const float* __restrict__ gscr, const int* __restrict__ batch,
                         const float* __restrict__ bf, float* __restrict__ out) {
    const int g = threadIdx.x;   // 128
    int lo = 0, hi = NN;
    while (lo < hi) { int m = (lo + hi) >> 1; if (batch[m] < g) lo = m + 1; else hi = m; }
    int lo2 = lo, hi2 = NN;
    while (lo2 < hi2) { int m = (lo2 + hi2) >> 1; if (batch[m] < g + 1) lo2 = m + 1; else hi2 = m; }
    const float inv = 1.f / fmaxf((float)(lo2 - lo), 1.f);
    out[g * 2]     = gscr[g * 32]     * inv + bf[0];
    out[g * 2 + 1] = gscr[g * 32 + 1] * inv + bf[1];
}

extern "C" void kernel_launch(void* const* d_in, const int* in_sizes, int n_in,
                              void* d_out, int out_size, void* d_ws, size_t ws_size,
                              hipStream_t stream) {
    const float* x       = (const float*)d_in[0];
    const float* W1      = (const float*)d_in[1];
    const float* att_src = (const float*)d_in[2];
    const float* att_dst = (const float*)d_in[3];
    const float* b1      = (const float*)d_in[4];
    const float* W2      = (const float*)d_in[5];
    const float* b2      = (const float*)d_in[6];
    const float* Wf      = (const float*)d_in[7];
    const float* bf      = (const float*)d_in[8];
    const int*   ei      = (const int*)d_in[9];
    const int*   batch   = (const int*)d_in[10];
    float* out = (float*)d_out;

    // layout: descending alignment
    uint4* wf1       = (uint4*)d_ws;                                // [2048] W1 frags (32 KB)
    uint4* wf2       = wf1 + 2048;                                  // [2048] W2 frags (32 KB)
    uint2* ca        = (uint2*)(wf2 + 2048);                        // [NBUCK*BCAP] (src, alpha)
    unsigned int* ebuf = (unsigned int*)(ca + (size_t)NBUCK * BCAP);// [NBUCK*BCAP]
    unsigned char* h1b = (unsigned char*)(ebuf + (size_t)NBUCK * BCAP); // [NN*F] fp8 (8B-aligned)
    unsigned char* h2b = h1b + (size_t)NN * F;                      // [NN*F] fp8 pre-scaled
    unsigned short* csr16 = (unsigned short*)(h2b + (size_t)NN * F);// [NBUCK*BCAP] 2B src
    float* asrc      = (float*)(csr16 + (size_t)NBUCK * BCAP);      // [NN]
    float* adst      = asrc + NN;                                   // [NN]
    float* dinv      = adst + NN;                                   // [NN]
    float* gscr      = dinv + NN;                                   // [NG*32]
    int*   row_start = (int*)(gscr + NG * 32);                      // [NN]
    int*   deg       = row_start + NN;                              // [NN]
    int*   cnt       = deg + NN;                                    // [NBUCK]

    // one-shot weight packing (+ gscr/cnt zeroing)
    pack_wfrag2<<<17, 256, 0, stream>>>(W1, W2, wf1, gscr, cnt);
    // gemm1 and CSR scatter are independent: one fused dispatch
    gemm1_count_scatter<<<GB1 + NBE, 256, 0, stream>>>(x, wf1, (uint2*)h1b, att_src, att_dst,
                                                       asrc, adst, ei, cnt, ebuf);
    bucket_sort<<<NBUCK, 256, 0, stream>>>(ebuf, cnt, asrc, adst,
                                           row_start, ca, csr16, deg, dinv);
    gat_gemm2<<<NN / 16, 256, 0, stream>>>(row_start, deg, ca, h1b, b1, wf2, dinv, h2b);
    gcn_gather_pool<<<NN / 16, 256, 0, stream>>>(row_start, deg, csr16, dinv, h2b, b2,
                                                 batch, Wf, gscr);
    finalize<<<1, NG, 0, stream>>>(gscr, batch, bf, out);
}